// Round 3
// baseline (359.816 us; speedup 1.0000x reference)
//
#include <hip/hip_runtime.h>
#include <math.h>

#define NB 16
#define TT 800
#define FF 90
#define SS 128
#define LL 200
#define NEGV (-1e30f)

#define DNODES 16    // den nodes per utterance
#define DNDRX 50     // den frames per node (16*50 = 800)
#define QNODES 32    // num nodes per utterance
#define QDRX 25      // num frames per node
#define BROW 26      // band diagonals (QDRX+1)
#define NEGH (-60000.0f)
#define RST 68       // den X row stride in u32 words within a wave region
#define EPAD 228     // padded num emission row (200 + 26 + slack)
#define LN2F 0.69314718055994531f
#define LOG2E 1.4426950408889634f

typedef __attribute__((ext_vector_type(8))) short short8;
typedef __attribute__((ext_vector_type(4))) float float4v;

static __device__ __forceinline__ unsigned short f2bf(float x) {
    union { float f; unsigned u; } v; v.f = x;
    unsigned r = (v.u + 0x7FFFu + ((v.u >> 16) & 1u)) >> 16;
    return (unsigned short)r;
}
// truncating bf16 pair pack in ONE VALU op (v_perm_b32), non-negative values
static __device__ __forceinline__ unsigned packperm(float a, float b) {
    return __builtin_amdgcn_perm(__float_as_uint(b), __float_as_uint(a),
                                 0x07060302u);
}

// ======================= Fused kernel =======================================
// 512 blocks x 512 threads, dens (blocks 0..255) dispatched first.
//   den block: per-wave 16-row x 128-col running product, zero barriers in
//              the t-loop (validated r2). A-fragments staged in-block via LDS.
//   num block: TWO band nodes, column-parallel, triangle-cut inner loop.
// Last-block-per-utterance runs the chain inline (atomic counters, no spins);
// last chain runs finalize. One kernel launch total.
__global__ __launch_bounds__(512, 2) void mmi_all(
    const float* __restrict__ x,
    const int*   __restrict__ sup,
    const float* __restrict__ trans,
    const int*   __restrict__ den_labels,
    const int*   __restrict__ num_labels,
    const int*   __restrict__ num_lens,
    unsigned*    __restrict__ Pout,     // [NB*DNODES][8192] u32 (bf16 pairs)
    float*       __restrict__ scales8,  // [NB*DNODES][8] pow2 exps per row grp
    _Float16*    __restrict__ Bd,       // [NB*QNODES][201][BROW]
    float*       __restrict__ dsc,      // [0..15] den, [16..31] num scores
    int*         __restrict__ ctr,      // [0..15] den, [16..31] num, [32] all
    float*       __restrict__ out)
{
    __shared__ __align__(16) unsigned char SMEM[60448];
    __shared__ int sflag;
    const int tid = threadIdx.x;
    int u;   // utterance of this block

    if (blockIdx.x < NB * DNODES) {
        // ================= den node product =================
        const int bid = blockIdx.x;
        u = bid >> 4;
        const int nd = bid & 15;
        const int t0 = nd * DNDRX;
        const int nf = sup[u * 3 + 2];
        unsigned* Pg = Pout + (size_t)bid * 8192;

        if (t0 >= nf) {   // frozen node -> identity
            #pragma unroll
            for (int k2 = 0; k2 < 16; ++k2) {
                const int ww = tid + k2 * 512;
                const int row = ww >> 6, colw = ww & 63;
                unsigned val = 0;
                if (row == 2 * colw)     val |= 0x3F80u;
                if (row == 2 * colw + 1) val |= 0x3F800000u;
                Pg[ww] = val;
            }
            if (tid < 8) scales8[bid * 8 + tid] = 0.0f;
        } else {
            unsigned* AFs = (unsigned*)SMEM;              // 8192 u32 = 32 KB
            const int w = tid >> 6, l = tid & 63;
            const int m15 = l & 15, q = l >> 4;

            // ---- stage A = exp(T)^T fragments through LDS (one-shot) ----
            #pragma unroll
            for (int i = 0; i < 16; ++i) {
                const int wi = tid + i * 512;             // 0..8191
                const int f  = wi >> 2, j2 = wi & 3;
                const int fl = f & 63, kc = (f >> 6) & 3, mt = f >> 8;
                const int col = mt * 16 + (fl & 15);
                const int krow = kc * 32 + (fl >> 4) * 8 + 2 * j2;
                const float a = __expf(trans[(krow    ) * SS + col]);
                const float b = __expf(trans[(krow + 1) * SS + col]);
                AFs[wi] = (unsigned)f2bf(a) | ((unsigned)f2bf(b) << 16);
            }
            __syncthreads();
            short8 afrag[8][4];
            #pragma unroll
            for (int mt = 0; mt < 8; ++mt)
                #pragma unroll
                for (int kc = 0; kc < 4; ++kc)
                    afrag[mt][kc] =
                        *(const short8*)(AFs + ((mt * 4 + kc) * 64 + l) * 4);
            __syncthreads();   // AFs region reused below

            unsigned* Xs  = (unsigned*)SMEM;              // 34816 B
            float* ptab   = (float*)(SMEM + 34816);       // 25600 B

            for (int idx = tid; idx < DNDRX * SS; idx += 512) {
                const int tt = idx >> 7, d = idx & 127;
                const int fr = min(t0 + tt, TT - 1);
                ptab[idx] = __expf(x[((size_t)u * TT + fr) * FF + den_labels[d]]);
            }
            __syncthreads();

            // per-wave init of own 16 rows: X0 = exp(T) * p0
            unsigned* Xw = Xs + w * (16 * RST);
            {
                const float p0 = ptab[2 * l], p1 = ptab[2 * l + 1];
                #pragma unroll
                for (int k2 = 0; k2 < 16; ++k2) {
                    const int R = w * 16 + k2;
                    const float2 t2 = ((const float2*)trans)[R * 64 + l];
                    Xw[k2 * RST + l] = packperm(__expf(t2.x) * p0,
                                                __expf(t2.y) * p1);
                }
            }

            const unsigned short* XwH = (const unsigned short*)Xw;
            const int kmax = min(DNDRX, nf - t0);
            int eacc = 0;
            float redmax = 1.0f;

            for (int k = 1; k < kmax; ++k) {
                const bool dosc = ((k & 3) == 0);
                float sc = 1.0f;
                if (dosc) {
                    const float mm = fmaxf(redmax, 1e-37f);
                    const int e = (int)((__float_as_uint(mm) >> 23) & 255u);
                    sc = __uint_as_float((unsigned)(254 - e) << 23);
                    eacc += (e - 127);
                }

                short8 bf[4];
                #pragma unroll
                for (int kc = 0; kc < 4; ++kc)
                    bf[kc] = *(const short8*)(XwH + m15 * (2 * RST) +
                                              kc * 32 + q * 8);

                float4v acc[8];
                #pragma unroll
                for (int mt = 0; mt < 8; ++mt) {
                    float4v z = {0.f, 0.f, 0.f, 0.f};
                    acc[mt] = z;
                }
                #pragma unroll
                for (int kc = 0; kc < 4; ++kc)
                    #pragma unroll
                    for (int mt = 0; mt < 8; ++mt)
                        acc[mt] = __builtin_amdgcn_mfma_f32_16x16x32_bf16(
                            afrag[mt][kc], bf[kc], acc[mt], 0, 0, 0);

                const bool dmax = ((k & 3) == 3);
                float vmax = 0.0f;
                #pragma unroll
                for (int mt = 0; mt < 8; ++mt) {
                    float4 pc = *(const float4*)(ptab + k * SS + mt * 16 + 4 * q);
                    if (dosc) { pc.x *= sc; pc.y *= sc; pc.z *= sc; pc.w *= sc; }
                    acc[mt][0] *= pc.x;
                    acc[mt][1] *= pc.y;
                    acc[mt][2] *= pc.z;
                    acc[mt][3] *= pc.w;
                    if (dmax)
                        vmax = fmaxf(vmax,
                            fmaxf(fmaxf(acc[mt][0], acc[mt][1]),
                                  fmaxf(acc[mt][2], acc[mt][3])));
                }
                if (dmax) {
                    #pragma unroll
                    for (int off = 32; off >= 1; off >>= 1)
                        vmax = fmaxf(vmax, __shfl_xor(vmax, off, 64));
                    redmax = vmax;
                }

                #pragma unroll
                for (int mt = 0; mt < 8; ++mt) {
                    uint2 pk;
                    pk.x = packperm(acc[mt][0], acc[mt][1]);
                    pk.y = packperm(acc[mt][2], acc[mt][3]);
                    *(uint2*)(Xw + m15 * RST + mt * 8 + 2 * q) = pk;
                }
            }

            #pragma unroll
            for (int k2 = 0; k2 < 16; ++k2)
                Pg[(w * 16 + k2) * 64 + l] = Xw[k2 * RST + l];
            if (l == 0) scales8[bid * 8 + w] = (float)eacc;
        }

        // -------- completion + inline den chain (last block of u) --------
        __threadfence();
        if (tid == 0) sflag = (atomicAdd(&ctr[u], 1) == DNODES - 1);
        __syncthreads();
        if (!sflag) return;
        {
            float* sh_v    = (float*)SMEM;                // 512 B
            float* sh_part = (float*)(SMEM + 512);        // 4096 B
            float* sh_red  = (float*)(SMEM + 4608);       // 8 B
            __syncthreads();  // SMEM reuse

            const bool act = tid < 256;
            const int gg = tid & 31, c = tid >> 5;        // c 0..15 (use <8)
            const unsigned short* Pu =
                (const unsigned short*)(Pout + (size_t)u * DNODES * 8192);

            if (tid < SS) sh_v[tid] = (tid == 0) ? 1.0f : 0.0f;
            int   e2acc = 0;
            float sscal = 0.0f;

            uint2 curm[16], nxt[16];
            if (act) {
                #pragma unroll
                for (int j = 0; j < 16; ++j)
                    curm[j] = *(const uint2*)(Pu + (16 * c + j) * SS + 4 * gg);
            }
            __syncthreads();

            for (int i = 0; i < DNODES; ++i) {
                if (act && i + 1 < DNODES) {
                    const unsigned short* Pn = Pu + (size_t)(i + 1) * 16384;
                    #pragma unroll
                    for (int j = 0; j < 16; ++j)
                        nxt[j] = *(const uint2*)(Pn + (16 * c + j) * SS + 4 * gg);
                }
                float fgr = 0.0f;
                if (act) {
                    const float* s8 = scales8 + (size_t)(u * DNODES + i) * 8;
                    float gmax = s8[0];
                    #pragma unroll
                    for (int g2 = 1; g2 < 8; ++g2) gmax = fmaxf(gmax, s8[g2]);
                    fgr = __builtin_amdgcn_exp2f(s8[c & 7] - gmax);
                    sscal += gmax;
                }
                if (act) {
                    const float4* av = (const float4*)(sh_v + 16 * c);
                    float4 aa[4] = {av[0], av[1], av[2], av[3]};
                    const float* as = (const float*)aa;
                    float4 acc = make_float4(0.f, 0.f, 0.f, 0.f);
                    #pragma unroll
                    for (int j = 0; j < 16; ++j) {
                        const float e0 = __uint_as_float(curm[j].x << 16);
                        const float e1 = __uint_as_float(curm[j].x & 0xFFFF0000u);
                        const float e2 = __uint_as_float(curm[j].y << 16);
                        const float e3 = __uint_as_float(curm[j].y & 0xFFFF0000u);
                        acc.x = fmaf(as[j], e0, acc.x);
                        acc.y = fmaf(as[j], e1, acc.y);
                        acc.z = fmaf(as[j], e2, acc.z);
                        acc.w = fmaf(as[j], e3, acc.w);
                    }
                    acc.x *= fgr; acc.y *= fgr; acc.z *= fgr; acc.w *= fgr;
                    *(float4*)(sh_part + c * SS + 4 * gg) = acc;
                }
                __syncthreads();

                float v = 0.0f;
                if (tid < SS) {
                    float y = 0.0f;
                    #pragma unroll
                    for (int cc = 0; cc < 8; ++cc) y += sh_part[cc * SS + tid];
                    v = y;
                    float m = v;
                    #pragma unroll
                    for (int off = 32; off >= 1; off >>= 1)
                        m = fmaxf(m, __shfl_xor(m, off, 64));
                    if ((tid & 63) == 0) sh_red[tid >> 6] = m;
                }
                __syncthreads();
                if (tid < SS) {
                    const float mm = fmaxf(fmaxf(sh_red[0], sh_red[1]), 1e-37f);
                    const int e = (int)((__float_as_uint(mm) >> 23) & 255u);
                    const float inv = __uint_as_float((unsigned)(254 - e) << 23);
                    e2acc += (e - 127);
                    sh_v[tid] = v * inv;
                }
                if (act) {
                    #pragma unroll
                    for (int j = 0; j < 16; ++j) curm[j] = nxt[j];
                }
                __syncthreads();
            }

            if (tid < SS) {
                float s = sh_v[tid];
                #pragma unroll
                for (int off = 32; off >= 1; off >>= 1)
                    s += __shfl_xor(s, off, 64);
                if ((tid & 63) == 0) sh_red[tid >> 6] = s;
            }
            __syncthreads();
            if (tid == 0)
                dsc[u] = LN2F * ((float)e2acc + sscal) +
                         __logf(sh_red[0] + sh_red[1]);
        }
    } else {
        // ================= num band products: 2 nodes, column-parallel ======
        float* est = (float*)(SMEM + 16);          // [2][25][EPAD] f32

        const int qb    = blockIdx.x - NB * DNODES;
        const int slot0 = qb * 2;
        u = slot0 / QNODES;
        const int nd0   = slot0 - u * QNODES;
        const int nf    = sup[u * 3 + 2];
        const int* nlu  = num_labels + u * LL;

        for (int idx = tid; idx < 2 * QDRX * EPAD; idx += 512) {
            const int g   = idx / (QDRX * EPAD);
            const int rem = idx - g * (QDRX * EPAD);
            const int tt  = rem / EPAD;
            const int j   = rem - tt * EPAD;
            const int jj  = min(j, 199);
            const int fr  = min((nd0 + g) * QDRX + tt, TT - 1);
            est[idx] = x[((size_t)u * TT + fr) * FF + nlu[jj]] * LOG2E;
        }
        __syncthreads();

        {
            const int g  = tid >> 8;       // node half 0/1
            const int c  = tid & 255;      // band source column (row r = c+d)
            const int nd = nd0 + g;
            const int t0 = nd * QDRX;
            const int kmaxg = min(QDRX, max(nf - t0, 0));
            const float* eg = est + g * (QDRX * EPAD);

            float a[BROW];
            a[0] = 0.0f;
            #pragma unroll
            for (int d = 1; d < BROW; ++d) a[d] = NEGV;

            const float* etc = eg + (c - 1);
            for (int t = 0; t < kmaxg; ++t, etc += EPAD) {
                const int tc = t + 1;   // wave-uniform live-band bound
                #pragma unroll
                for (int d = BROW - 1; d >= 1; --d) {
                    if (d <= tc) {
                        const float e  = etc[d];
                        const float aa = a[d], bb = a[d - 1];
                        const float mx = fmaxf(aa, bb);
                        const float dd = fminf(aa, bb) - mx;
                        a[d] = e + mx +
                            __builtin_amdgcn_logf(
                                1.0f + __builtin_amdgcn_exp2f(dd));
                    }
                }
                a[0] = (c == 0) ? NEGV : (etc[0] + a[0]);
            }

            if (c <= 200) {
                _Float16* Bg = Bd + (size_t)(slot0 + g) * 201 * BROW;
                #pragma unroll
                for (int d = 0; d < BROW; ++d) {
                    const int r = c + d;
                    if (r <= 200) Bg[r * BROW + d] = (_Float16)fmaxf(a[d], NEGH);
                }
                if (c < BROW - 1) {   // fill k > r triangle
                    for (int kk = c + 1; kk < BROW; ++kk)
                        Bg[c * BROW + kk] = (_Float16)NEGH;
                }
            }
        }

        // -------- completion + inline num chain (last block of u) --------
        __threadfence();
        if (tid == 0) sflag = (atomicAdd(&ctr[NB + u], 1) == QNODES / 2 - 1);
        __syncthreads();
        if (!sflag) return;
        {
            float (*ab)[232] = (float (*)[232])SMEM;   // 2*232 f32
            __syncthreads();  // SMEM reuse

            const _Float16* Bu = Bd + (size_t)u * QNODES * 201 * BROW;
            const int r = tid;

            if (r < 232) { ab[0][r] = NEGV; ab[1][r] = NEGV; }
            float dv[BROW];
            if (r < 201) {
                #pragma unroll
                for (int k = 0; k < BROW; ++k) dv[k] = (float)Bu[r * BROW + k];
            }
            __syncthreads();
            if (r == 0) ab[0][QDRX] = 0.0f;   // alpha[0]=0 (log2), offset QDRX
            __syncthreads();

            int cur = 0;
            for (int nd = 0; nd < QNODES; ++nd) {
                _Float16 nx[BROW];
                if (nd + 1 < QNODES && r < 201) {
                    const _Float16* src = Bu + ((size_t)(nd + 1) * 201 + r) * BROW;
                    #pragma unroll
                    for (int k = 0; k < BROW; ++k) nx[k] = src[k];
                }
                float anew = NEGV;
                if (r < 201) {
                    float tr[BROW];
                    #pragma unroll
                    for (int k = 0; k < BROW; ++k)
                        tr[k] = dv[k] + ab[cur][QDRX + r - k];
                    float m = tr[0];
                    #pragma unroll
                    for (int k = 1; k < BROW; ++k) m = fmaxf(m, tr[k]);
                    float s = 0.0f;
                    #pragma unroll
                    for (int k = 0; k < BROW; ++k)
                        s += __builtin_amdgcn_exp2f(tr[k] - m);
                    anew = m + __builtin_amdgcn_logf(s);
                }
                if (r < 201) ab[cur ^ 1][QDRX + r] = anew;
                cur ^= 1;
                __syncthreads();
                if (r < 201) {
                    #pragma unroll
                    for (int k = 0; k < BROW; ++k) dv[k] = (float)nx[k];
                }
            }
            if (r == 0) dsc[NB + u] = ab[cur][QDRX + num_lens[u]] * LN2F;
        }
    }

    // ---------------- last chain runs finalize ----------------
    __threadfence();
    if (tid == 0) sflag = (atomicAdd(&ctr[2 * NB], 1) == 2 * NB - 1);
    __syncthreads();
    if (!sflag) return;
    __threadfence();
    if (tid < 64) {
        float tot_score = 0.0f, tot_frames = 0.0f, all_frames = 0.0f;
        if (tid < NB) {
            const float tot = dsc[NB + tid] - dsc[tid];
            const int nf = sup[tid * 3 + 2];
            const bool fin = isfinite(tot) && (tot > 0.5f * NEGV);
            tot_score  = fin ? tot : 0.0f;
            tot_frames = fin ? (float)nf : 0.0f;
            all_frames = (float)nf;
        }
        #pragma unroll
        for (int off = 32; off >= 1; off >>= 1) {
            tot_score  += __shfl_xor(tot_score, off, 64);
            tot_frames += __shfl_xor(tot_frames, off, 64);
            all_frames += __shfl_xor(all_frames, off, 64);
        }
        if (tid == 0) {
            out[0] = tot_score;
            out[1] = tot_frames;
            out[2] = all_frames;
        }
    }
}

// ======================= Finalize (fallback path only) ======================
__global__ void mmi_finalize(const float* __restrict__ sc,
                             const int* __restrict__ sup,
                             float* __restrict__ out)
{
    const int tid = threadIdx.x;
    float tot_score = 0.0f, tot_frames = 0.0f, all_frames = 0.0f;
    if (tid < NB) {
        const float tot = sc[NB + tid] - sc[tid];
        const int nf = sup[tid * 3 + 2];
        const bool fin = isfinite(tot) && (tot > 0.5f * NEGV);
        tot_score  = fin ? tot : 0.0f;
        tot_frames = fin ? (float)nf : 0.0f;
        all_frames = (float)nf;
    }
    #pragma unroll
    for (int off = 32; off >= 1; off >>= 1) {
        tot_score  += __shfl_xor(tot_score, off, 64);
        tot_frames += __shfl_xor(tot_frames, off, 64);
        all_frames += __shfl_xor(all_frames, off, 64);
    }
    if (tid == 0) {
        out[0] = tot_score;
        out[1] = tot_frames;
        out[2] = all_frames;
    }
}

// ======================= Fallback (validated round-4 kernel) =================
#define XBF (16 * FF)
__global__ __launch_bounds__(256) void mmi_forward_fb(
    const float* __restrict__ x, const int* __restrict__ sup,
    const float* __restrict__ trans, const int* __restrict__ den_labels,
    const int* __restrict__ num_labels, const int* __restrict__ num_lens,
    float* __restrict__ ws)
{
    const int tid = threadIdx.x;
    if (blockIdx.x < NB) {
        __shared__ float sh_v[SS];
        __shared__ float sh_part[8 * SS];
        __shared__ float sh_red[4];
        __shared__ __align__(16) float xbuf[2][XBF];
        const int n = blockIdx.x, nf = sup[n * 3 + 2];
        const int g = tid & 31, c = tid >> 5;
        float4 e[16];
        #pragma unroll
        for (int j = 0; j < 16; ++j) {
            const float4 t4 = *(const float4*)(trans + (size_t)(16 * c + j) * SS + 4 * g);
            e[j] = make_float4(__expf(t4.x), __expf(t4.y), __expf(t4.z), __expf(t4.w));
        }
        const int lab = (tid < SS) ? den_labels[tid & (SS - 1)] : 0;
        const float* xb = x + (size_t)n * TT * FF;
        {
            const float4* s0 = (const float4*)xb;
            float4 p0 = s0[tid]; float4 p1; if (tid < 104) p1 = s0[256 + tid];
            float4* d0 = (float4*)xbuf[0];
            d0[tid] = p0; if (tid < 104) d0[256 + tid] = p1;
        }
        if (tid < SS) sh_v[tid] = (tid == 0) ? 1.0f : 0.0f;
        float logM = 0.0f, v = 0.0f, pe = 0.0f;
        float4 pf0, pf1;
        __syncthreads();
        for (int t = 0; t < nf; ++t) {
            const int b = t >> 4;
            if (tid < SS) pe = __expf(xbuf[b & 1][(t & 15) * FF + lab]);
            float4 aa[4];
            { const float4* av = (const float4*)(sh_v + 16 * c);
              aa[0] = av[0]; aa[1] = av[1]; aa[2] = av[2]; aa[3] = av[3]; }
            const float* as = (const float*)aa;
            float4 acc = make_float4(0.f, 0.f, 0.f, 0.f);
            #pragma unroll
            for (int j = 0; j < 16; ++j) {
                acc.x = fmaf(as[j], e[j].x, acc.x); acc.y = fmaf(as[j], e[j].y, acc.y);
                acc.z = fmaf(as[j], e[j].z, acc.z); acc.w = fmaf(as[j], e[j].w, acc.w);
            }
            *(float4*)(sh_part + c * SS + 4 * g) = acc;
            if ((t & 15) == 8) {
                const int tn = (b + 1) * 16;
                if (tn < nf) {
                    const float4* s = (const float4*)(xb + (size_t)tn * FF);
                    pf0 = s[tid]; if (tid < 104) pf1 = s[256 + tid];
                }
            }
            __syncthreads();
            const bool rs = ((t & 15) == 15);
            if (tid < SS) {
                float y = 0.0f;
                #pragma unroll
                for (int cc = 0; cc < 8; ++cc) y += sh_part[cc * SS + tid];
                v = y * pe;
                if (rs) {
                    float m = v;
                    #pragma unroll
                    for (int off = 32; off >= 1; off >>= 1)
                        m = fmaxf(m, __shfl_xor(m, off, 64));
                    if ((tid & 63) == 0) sh_red[tid >> 6] = m;
                }
            }
            if (rs) {
                const int tn = (b + 1) * 16;
                if (tn < nf) {
                    float4* dst = (float4*)xbuf[(b + 1) & 1];
                    dst[tid] = pf0; if (tid < 104) dst[256 + tid] = pf1;
                }
                __syncthreads();
                if (tid < SS) {
                    float mm = fmaxf(fmaxf(sh_red[0], sh_red[1]), 1e-37f);
                    v *= (1.0f / mm); logM += __logf(mm);
                }
            }
            if (tid < SS) sh_v[tid] = v;
            __syncthreads();
        }
        if (tid < SS) {
            float ssum = v;
            #pragma unroll
            for (int off = 32; off >= 1; off >>= 1) ssum += __shfl_xor(ssum, off, 64);
            if ((tid & 63) == 0) sh_red[2 + (tid >> 6)] = ssum;
        }
        __syncthreads();
        if (tid == 0) ws[n] = logM + __logf(sh_red[2] + sh_red[3]);
    } else {
        const int w = tid >> 6, l = tid & 63;
        const int n = (blockIdx.x - NB) * 4 + w;
        const int nf = sup[n * 3 + 2];
        const float* xb = x + (size_t)n * TT * FF;
        const int* nl = num_labels + n * LL;
        int li[4];
        #pragma unroll
        for (int k = 0; k < 4; ++k) li[k] = nl[min(4 * l + k, LL - 1)];
        float a4[4] = {NEGV, NEGV, NEGV, NEGV};
        float ea[4], eb[4];
        #pragma unroll
        for (int k = 0; k < 4; ++k) ea[k] = xb[li[k]];
        { const float* xr = xb + (size_t)min(1, nf - 1) * FF;
          #pragma unroll
          for (int k = 0; k < 4; ++k) eb[k] = xr[li[k]]; }
        auto step = [&](float (&ee)[4], int t) {
            float left = __shfl_up(a4[3], 1, 64);
            if (l == 0) left = (t == 0) ? 0.0f : NEGV;
            float prev = left;
            #pragma unroll
            for (int k = 0; k < 4; ++k) {
                const float a = a4[k], b = prev;
                const float mx = fmaxf(a, b), mn = fminf(a, b);
                const float nv = mx + __logf(1.0f + __expf(mn - mx)) + ee[k];
                prev = a4[k]; a4[k] = nv;
            }
            const int t2 = min(t + 2, nf - 1);
            const float* xr = xb + (size_t)t2 * FF;
            #pragma unroll
            for (int k = 0; k < 4; ++k) ee[k] = xr[li[k]];
        };
        int t = 0;
        while (t < nf) { step(ea, t); ++t; if (t >= nf) break; step(eb, t); ++t; }
        const int idx = num_lens[n] - 1;
        if ((idx >> 2) == l) {
            const int kk = idx & 3;
            float vv = (kk == 0) ? a4[0] : (kk == 1) ? a4[1] : (kk == 2) ? a4[2] : a4[3];
            ws[NB + n] = vv;
        }
    }
}

extern "C" void kernel_launch(void* const* d_in, const int* in_sizes, int n_in,
                              void* d_out, int out_size, void* d_ws, size_t ws_size,
                              hipStream_t stream) {
    const float* x          = (const float*)d_in[0];
    const int*   sup        = (const int*)d_in[1];
    const float* trans      = (const float*)d_in[2];
    const int*   den_labels = (const int*)d_in[3];
    const int*   num_labels = (const int*)d_in[4];
    const int*   num_lens   = (const int*)d_in[5];
    float* out = (float*)d_out;

    const size_t PBYTES = (size_t)NB * DNODES * 32768;              // 8,388,608
    const size_t BBYTES = (size_t)NB * QNODES * 201 * BROW * 2;     // 5,351,424
    const size_t SCB    = (size_t)NB * DNODES * 8 * sizeof(float);  // 32,768
    const size_t SOFF   = PBYTES + BBYTES;
    const size_t DOFF   = SOFF + SCB;              // dsc (64 floats)
    const size_t COFF   = DOFF + 256;              // counters (64 ints)
    const size_t NEEDED = COFF + 256;

    if (ws_size >= NEEDED) {
        unsigned*  Pout    = (unsigned*)d_ws;
        _Float16*  Bd      = (_Float16*)((char*)d_ws + PBYTES);
        float*     scales8 = (float*)((char*)d_ws + SOFF);
        float*     dsc     = (float*)((char*)d_ws + DOFF);
        int*       ctr     = (int*)((char*)d_ws + COFF);
        hipMemsetAsync(ctr, 0, 256, stream);
        mmi_all<<<dim3(512), dim3(512), 0, stream>>>(
            x, sup, trans, den_labels, num_labels, num_lens,
            Pout, scales8, Bd, dsc, ctr, out);
    } else {
        float* ws = (float*)d_ws;
        mmi_forward_fb<<<dim3(20), dim3(256), 0, stream>>>(
            x, sup, trans, den_labels, num_labels, num_lens, ws);
        mmi_finalize<<<dim3(1), dim3(64), 0, stream>>>(ws, sup, out);
    }
}

// Round 4
// 182.974 us; speedup vs baseline: 1.9665x; 1.9665x over previous
//
#include <hip/hip_runtime.h>
#include <math.h>

#define NB 16
#define TT 800
#define FF 90
#define SS 128
#define LL 200
#define NEGV (-1e30f)

#define DNODES 16    // den nodes per utterance
#define DNDRX 50     // den frames per node (16*50 = 800)
#define PTROWS 25    // ptab rows resident (two-phase staging)
#define QNODES 32    // num nodes per utterance
#define QDRX 25      // num frames per node
#define BROW 26      // band diagonals (QDRX+1)
#define NEGH (-60000.0f)
#define RST 68       // den X row stride in u32 words within a wave region
#define EPAD 228     // padded num emission row (200 + 26 + slack)
#define LN2F 0.69314718055994531f
#define LOG2E 1.4426950408889634f

typedef __attribute__((ext_vector_type(8))) short short8;
typedef __attribute__((ext_vector_type(4))) float float4v;

static __device__ __forceinline__ unsigned short f2bf(float x) {
    union { float f; unsigned u; } v; v.f = x;
    unsigned r = (v.u + 0x7FFFu + ((v.u >> 16) & 1u)) >> 16;
    return (unsigned short)r;
}
// truncating bf16 pair pack in ONE VALU op (v_perm_b32), non-negative values
static __device__ __forceinline__ unsigned packperm(float a, float b) {
    return __builtin_amdgcn_perm(__float_as_uint(b), __float_as_uint(a),
                                 0x07060302u);
}

// ======================= Prep: A fragments ==================================
// AF[(mt*4+kc)*64 + l] = short8 bf16 fragment of exp(trans) in MFMA A layout:
//   element j = exp(trans[(kc*32 + (l>>4)*8 + j)*SS + mt*16 + (l&15)])
__global__ __launch_bounds__(256) void mmi_prep(const float* __restrict__ trans,
                                                unsigned* __restrict__ AF) {
    const int idx = blockIdx.x * 256 + threadIdx.x;   // 0..2047
    const int l  = idx & 63, fk = idx >> 6;           // fk = mt*4+kc
    const int mt = fk >> 2, kc = fk & 3;
    const int q  = l >> 4,  m15 = l & 15;
    unsigned wv[4];
    #pragma unroll
    for (int j2 = 0; j2 < 4; ++j2) {
        const float a = __expf(trans[(kc * 32 + q * 8 + 2 * j2    ) * SS + mt * 16 + m15]);
        const float b = __expf(trans[(kc * 32 + q * 8 + 2 * j2 + 1) * SS + mt * 16 + m15]);
        wv[j2] = (unsigned)f2bf(a) | ((unsigned)f2bf(b) << 16);
    }
    *(uint4*)(AF + 4 * idx) = make_uint4(wv[0], wv[1], wv[2], wv[3]);
}

// ======================= Kernel A ===========================================
// 512 blocks x 512 threads (8 waves), LDS <= 47.6 KB -> 3 blocks/CU (24
// waves/CU, 6/SIMD) for latency hiding. Dens dispatch first.
//   blockIdx <  256 -> den node: each wave owns 16 X-rows x 128 cols, ZERO
//       barriers in the t-loop (rows independent; wave round-trips its own
//       LDS region). ptab staged in two 25-frame phases (f32 precision).
//   blockIdx >= 256 -> TWO num band nodes, column-parallel, triangle-cut
//       inner loop (only live diagonals d <= t+1 are updated).
__global__ __launch_bounds__(512, 2) void mmi_nodes(
    const float* __restrict__ x,
    const int*   __restrict__ sup,
    const float* __restrict__ trans,
    const int*   __restrict__ den_labels,
    const int*   __restrict__ num_labels,
    const unsigned* __restrict__ AF,    // 2048 x 16B prepped A fragments
    unsigned*    __restrict__ Pout,     // [NB*DNODES][8192] u32 (bf16 pairs)
    float*       __restrict__ scales8,  // [NB*DNODES][8] pow2 exps per row grp
    _Float16*    __restrict__ Bd)       // [NB*QNODES][201][BROW]
{
    __shared__ __align__(16) unsigned char SMEM[47616];
    const int tid = threadIdx.x;

    if (blockIdx.x < NB * DNODES) {
        // ---------------- den node product ----------------
        unsigned* Xs  = (unsigned*)SMEM;              // 8 * 16*RST*4 = 34816 B
        float* ptab   = (float*)(SMEM + 34816);       // 25*128*4 = 12800 B

        const int bid = blockIdx.x;
        const int u  = bid >> 4;
        const int nd = bid & 15;
        const int t0 = nd * DNDRX;
        const int nf = sup[u * 3 + 2];
        unsigned* Pg = Pout + (size_t)bid * 8192;

        if (t0 >= nf) {   // frozen node -> identity
            #pragma unroll
            for (int k2 = 0; k2 < 16; ++k2) {
                const int ww = tid + k2 * 512;
                const int row = ww >> 6, colw = ww & 63;
                unsigned val = 0;
                if (row == 2 * colw)     val |= 0x3F80u;
                if (row == 2 * colw + 1) val |= 0x3F800000u;
                Pg[ww] = val;
            }
            if (tid < 8) scales8[bid * 8 + tid] = 0.0f;
            return;
        }

        const int w = tid >> 6, l = tid & 63;
        const int m15 = l & 15, q = l >> 4;

        // stage emissions phase A: frames t0..t0+24
        for (int idx = tid; idx < PTROWS * SS; idx += 512) {
            const int tt = idx >> 7, d = idx & 127;
            const int fr = min(t0 + tt, TT - 1);
            ptab[idx] = __expf(x[((size_t)u * TT + fr) * FF + den_labels[d]]);
        }
        __syncthreads();

        // per-wave init of own 16 rows: X0 = exp(T) * p0
        unsigned* Xw = Xs + w * (16 * RST);
        {
            const float p0 = ptab[2 * l], p1 = ptab[2 * l + 1];
            #pragma unroll
            for (int k2 = 0; k2 < 16; ++k2) {
                const int R = w * 16 + k2;
                const float2 t2 = ((const float2*)trans)[R * 64 + l];
                Xw[k2 * RST + l] = packperm(__expf(t2.x) * p0,
                                            __expf(t2.y) * p1);
            }
        }

        // A = exp(T)^T fragments, prepped layout: 32 coalesced 16B loads
        short8 afrag[8][4];
        #pragma unroll
        for (int mt = 0; mt < 8; ++mt)
            #pragma unroll
            for (int kc = 0; kc < 4; ++kc)
                afrag[mt][kc] = *(const short8*)(AF + ((mt * 4 + kc) * 64 + l) * 4);

        const unsigned short* XwH = (const unsigned short*)Xw;
        const int kmax = min(DNDRX, nf - t0);
        int eacc = 0;
        float redmax = 1.0f;

        int kbeg = 1;
        for (int ph = 0; ph < 2 && kbeg < kmax; ++ph) {
            const int kend = min(kmax, PTROWS * (ph + 1));
            const int kofs = ph * PTROWS;
            if (ph == 1) {
                __syncthreads();   // all waves done reading phase-A ptab
                for (int idx = tid; idx < PTROWS * SS; idx += 512) {
                    const int tt = PTROWS + (idx >> 7), d = idx & 127;
                    const int fr = min(t0 + tt, TT - 1);
                    ptab[idx] = __expf(x[((size_t)u * TT + fr) * FF +
                                         den_labels[d]]);
                }
                __syncthreads();
            }

            for (int k = kbeg; k < kend; ++k) {
                // pow2 renorm every 4th step, per-wave
                const bool dosc = ((k & 3) == 0);
                float sc = 1.0f;
                if (dosc) {
                    const float mm = fmaxf(redmax, 1e-37f);
                    const int e = (int)((__float_as_uint(mm) >> 23) & 255u);
                    sc = __uint_as_float((unsigned)(254 - e) << 23);
                    eacc += (e - 127);
                }

                short8 bf[4];
                #pragma unroll
                for (int kc = 0; kc < 4; ++kc)
                    bf[kc] = *(const short8*)(XwH + m15 * (2 * RST) +
                                              kc * 32 + q * 8);

                float4v acc[8];
                #pragma unroll
                for (int mt = 0; mt < 8; ++mt) {
                    float4v z = {0.f, 0.f, 0.f, 0.f};
                    acc[mt] = z;
                }
                #pragma unroll
                for (int kc = 0; kc < 4; ++kc)
                    #pragma unroll
                    for (int mt = 0; mt < 8; ++mt)
                        acc[mt] = __builtin_amdgcn_mfma_f32_16x16x32_bf16(
                            afrag[mt][kc], bf[kc], acc[mt], 0, 0, 0);

                // emission (pre-scaled by sc) + optional vmax for next renorm
                const bool dmax = ((k & 3) == 3);
                float vmax = 0.0f;
                #pragma unroll
                for (int mt = 0; mt < 8; ++mt) {
                    float4 pc = *(const float4*)(ptab + (k - kofs) * SS +
                                                 mt * 16 + 4 * q);
                    if (dosc) { pc.x *= sc; pc.y *= sc; pc.z *= sc; pc.w *= sc; }
                    acc[mt][0] *= pc.x;
                    acc[mt][1] *= pc.y;
                    acc[mt][2] *= pc.z;
                    acc[mt][3] *= pc.w;
                    if (dmax)
                        vmax = fmaxf(vmax,
                            fmaxf(fmaxf(acc[mt][0], acc[mt][1]),
                                  fmaxf(acc[mt][2], acc[mt][3])));
                }
                if (dmax) {
                    #pragma unroll
                    for (int off = 32; off >= 1; off >>= 1)
                        vmax = fmaxf(vmax, __shfl_xor(vmax, off, 64));
                    redmax = vmax;
                }

                // in-place write; same-wave lgkmcnt ordering, no barrier
                #pragma unroll
                for (int mt = 0; mt < 8; ++mt) {
                    uint2 pk;
                    pk.x = packperm(acc[mt][0], acc[mt][1]);
                    pk.y = packperm(acc[mt][2], acc[mt][3]);
                    *(uint2*)(Xw + m15 * RST + mt * 8 + 2 * q) = pk;
                }
            }
            kbeg = kend;
        }

        // epilogue: wave writes its own rows
        #pragma unroll
        for (int k2 = 0; k2 < 16; ++k2)
            Pg[(w * 16 + k2) * 64 + l] = Xw[k2 * RST + l];
        if (l == 0) scales8[bid * 8 + w] = (float)eacc;
        return;
    }

    // ---------------- num band products: 2 nodes/block, column-parallel -----
    {
        float* est = (float*)(SMEM + 16);          // [2][25][EPAD] f32

        const int qb    = blockIdx.x - NB * DNODES;
        const int slot0 = qb * 2;
        const int u     = slot0 / QNODES;          // both nodes in same utt
        const int nd0   = slot0 - u * QNODES;
        const int nf    = sup[u * 3 + 2];
        const int* nlu  = num_labels + u * LL;

        for (int idx = tid; idx < 2 * QDRX * EPAD; idx += 512) {
            const int g   = idx / (QDRX * EPAD);
            const int rem = idx - g * (QDRX * EPAD);
            const int tt  = rem / EPAD;
            const int j   = rem - tt * EPAD;
            const int jj  = min(j, 199);
            const int fr  = min((nd0 + g) * QDRX + tt, TT - 1);
            est[idx] = x[((size_t)u * TT + fr) * FF + nlu[jj]] * LOG2E;
        }
        __syncthreads();

        const int g  = tid >> 8;       // node half 0/1
        const int c  = tid & 255;      // band source column (row r = c + d)
        const int nd = nd0 + g;
        const int t0 = nd * QDRX;
        const int kmaxg = min(QDRX, max(nf - t0, 0));
        const float* eg = est + g * (QDRX * EPAD);

        // a[d] = B[c+d][d]: forward alpha of a unit mass started at row c.
        float a[BROW];
        a[0] = 0.0f;
        #pragma unroll
        for (int d = 1; d < BROW; ++d) a[d] = NEGV;

        const float* etc = eg + (c - 1);
        for (int t = 0; t < kmaxg; ++t, etc += EPAD) {
            const int tc = t + 1;   // wave-uniform live-band bound
            #pragma unroll
            for (int d = BROW - 1; d >= 1; --d) {
                if (d <= tc) {
                    const float e  = etc[d];    // emission of row c+d
                    const float aa = a[d], bb = a[d - 1];
                    const float mx = fmaxf(aa, bb);
                    const float dd = fminf(aa, bb) - mx;
                    a[d] = e + mx +
                           __builtin_amdgcn_logf(
                               1.0f + __builtin_amdgcn_exp2f(dd));
                }
            }
            // d = 0: self-loop at row c (row 0 cannot persist)
            a[0] = (c == 0) ? NEGV : (etc[0] + a[0]);
        }

        if (c <= 200) {
            _Float16* Bg = Bd + (size_t)(slot0 + g) * 201 * BROW;
            #pragma unroll
            for (int d = 0; d < BROW; ++d) {
                const int r = c + d;
                if (r <= 200) Bg[r * BROW + d] = (_Float16)fmaxf(a[d], NEGH);
            }
            if (c < BROW - 1) {   // fill k > r triangle (unreachable transfers)
                for (int kk = c + 1; kk < BROW; ++kk)
                    Bg[c * BROW + kk] = (_Float16)NEGH;
            }
        }
    }
}

// ======================= Kernel B: chains ====================================
__global__ __launch_bounds__(256) void mmi_chain(
    const unsigned short* __restrict__ Pmat,   // [16][DNODES][128*128] bf16
    const _Float16* __restrict__ Bd,           // [16][QNODES][201][BROW]
    const float* __restrict__ scales8,         // [16*DNODES][8]
    const int* __restrict__ num_lens,
    float* __restrict__ dsc)                   // [0..15] den, [16..31] num
{
    __shared__ float sh_v[SS];
    __shared__ float sh_part[8 * SS];
    __shared__ float sh_red[2];
    __shared__ float ab[2][232];

    const int tid = threadIdx.x;

    if (blockIdx.x < NB) {
        const int u = blockIdx.x;
        const int gg = tid & 31, c = tid >> 5;
        const unsigned short* Pu = Pmat + (size_t)u * DNODES * 16384;

        if (tid < SS) sh_v[tid] = (tid == 0) ? 1.0f : 0.0f;
        int   e2acc = 0;
        float sscal = 0.0f;

        uint2 curm[16], nxt[16];
        #pragma unroll
        for (int j = 0; j < 16; ++j)
            curm[j] = *(const uint2*)(Pu + (16 * c + j) * SS + 4 * gg);
        __syncthreads();

        for (int i = 0; i < DNODES; ++i) {
            if (i + 1 < DNODES) {
                const unsigned short* Pn = Pu + (size_t)(i + 1) * 16384;
                #pragma unroll
                for (int j = 0; j < 16; ++j)
                    nxt[j] = *(const uint2*)(Pn + (16 * c + j) * SS + 4 * gg);
            }
            // per-row-group pow2 scales of this node
            const float* s8 = scales8 + (size_t)(u * DNODES + i) * 8;
            float gmax = s8[0];
            #pragma unroll
            for (int g2 = 1; g2 < 8; ++g2) gmax = fmaxf(gmax, s8[g2]);
            const float fgr = __builtin_amdgcn_exp2f(s8[c] - gmax);
            sscal += gmax;

            const float4* av = (const float4*)(sh_v + 16 * c);
            float4 aa[4] = {av[0], av[1], av[2], av[3]};
            const float* as = (const float*)aa;
            float4 acc = make_float4(0.f, 0.f, 0.f, 0.f);
            #pragma unroll
            for (int j = 0; j < 16; ++j) {
                const float e0 = __uint_as_float(curm[j].x << 16);
                const float e1 = __uint_as_float(curm[j].x & 0xFFFF0000u);
                const float e2 = __uint_as_float(curm[j].y << 16);
                const float e3 = __uint_as_float(curm[j].y & 0xFFFF0000u);
                acc.x = fmaf(as[j], e0, acc.x);
                acc.y = fmaf(as[j], e1, acc.y);
                acc.z = fmaf(as[j], e2, acc.z);
                acc.w = fmaf(as[j], e3, acc.w);
            }
            acc.x *= fgr; acc.y *= fgr; acc.z *= fgr; acc.w *= fgr;
            *(float4*)(sh_part + c * SS + 4 * gg) = acc;
            __syncthreads();

            float v = 0.0f;
            if (tid < SS) {
                float y = 0.0f;
                #pragma unroll
                for (int cc = 0; cc < 8; ++cc) y += sh_part[cc * SS + tid];
                v = y;
                float m = v;
                #pragma unroll
                for (int off = 32; off >= 1; off >>= 1)
                    m = fmaxf(m, __shfl_xor(m, off, 64));
                if ((tid & 63) == 0) sh_red[tid >> 6] = m;
            }
            __syncthreads();
            if (tid < SS) {
                const float mm = fmaxf(fmaxf(sh_red[0], sh_red[1]), 1e-37f);
                const int e = (int)((__float_as_uint(mm) >> 23) & 255u);
                const float inv = __uint_as_float((unsigned)(254 - e) << 23);
                e2acc += (e - 127);
                sh_v[tid] = v * inv;
            }
            #pragma unroll
            for (int j = 0; j < 16; ++j) curm[j] = nxt[j];
            __syncthreads();
        }

        if (tid < SS) {
            float s = sh_v[tid];
            #pragma unroll
            for (int off = 32; off >= 1; off >>= 1)
                s += __shfl_xor(s, off, 64);
            if ((tid & 63) == 0) sh_red[tid >> 6] = s;
        }
        __syncthreads();
        if (tid == 0)
            dsc[u] = LN2F * ((float)e2acc + sscal) + __logf(sh_red[0] + sh_red[1]);
    } else {
        // ---------------- num chain: band matvecs ----------------
        const int u = blockIdx.x - NB;
        const _Float16* Bu = Bd + (size_t)u * QNODES * 201 * BROW;
        const int r = tid;

        if (r < 232) { ab[0][r] = NEGV; ab[1][r] = NEGV; }
        float dv[BROW];
        if (r < 201) {
            #pragma unroll
            for (int k = 0; k < BROW; ++k) dv[k] = (float)Bu[r * BROW + k];
        }
        __syncthreads();
        if (r == 0) ab[0][QDRX] = 0.0f;    // alpha[0] = 0 (log2), offset QDRX
        __syncthreads();

        int cur = 0;
        for (int nd = 0; nd < QNODES; ++nd) {
            _Float16 nx[BROW];
            if (nd + 1 < QNODES && r < 201) {
                const _Float16* src = Bu + ((size_t)(nd + 1) * 201 + r) * BROW;
                #pragma unroll
                for (int k = 0; k < BROW; ++k) nx[k] = src[k];
            }
            float anew = NEGV;
            if (r < 201) {
                float tr[BROW];
                #pragma unroll
                for (int k = 0; k < BROW; ++k)
                    tr[k] = dv[k] + ab[cur][QDRX + r - k];
                float m = tr[0];
                #pragma unroll
                for (int k = 1; k < BROW; ++k) m = fmaxf(m, tr[k]);
                float s = 0.0f;
                #pragma unroll
                for (int k = 0; k < BROW; ++k)
                    s += __builtin_amdgcn_exp2f(tr[k] - m);
                anew = m + __builtin_amdgcn_logf(s);
            }
            if (r < 201) ab[cur ^ 1][QDRX + r] = anew;
            cur ^= 1;
            __syncthreads();
            if (r < 201) {
                #pragma unroll
                for (int k = 0; k < BROW; ++k) dv[k] = (float)nx[k];
            }
        }
        if (r == 0) dsc[NB + u] = ab[cur][QDRX + num_lens[u]] * LN2F;
    }
}

// ======================= Finalize ============================================
__global__ void mmi_finalize(const float* __restrict__ sc,
                             const int* __restrict__ sup,
                             float* __restrict__ out)
{
    const int tid = threadIdx.x;
    float tot_score = 0.0f, tot_frames = 0.0f, all_frames = 0.0f;
    if (tid < NB) {
        const float tot = sc[NB + tid] - sc[tid];
        const int nf = sup[tid * 3 + 2];
        const bool fin = isfinite(tot) && (tot > 0.5f * NEGV);
        tot_score  = fin ? tot : 0.0f;
        tot_frames = fin ? (float)nf : 0.0f;
        all_frames = (float)nf;
    }
    #pragma unroll
    for (int off = 32; off >= 1; off >>= 1) {
        tot_score  += __shfl_xor(tot_score, off, 64);
        tot_frames += __shfl_xor(tot_frames, off, 64);
        all_frames += __shfl_xor(all_frames, off, 64);
    }
    if (tid == 0) {
        out[0] = tot_score;
        out[1] = tot_frames;
        out[2] = all_frames;
    }
}

// ======================= Fallback (validated round-4 kernel) =================
#define XBF (16 * FF)
__global__ __launch_bounds__(256) void mmi_forward_fb(
    const float* __restrict__ x, const int* __restrict__ sup,
    const float* __restrict__ trans, const int* __restrict__ den_labels,
    const int* __restrict__ num_labels, const int* __restrict__ num_lens,
    float* __restrict__ ws)
{
    const int tid = threadIdx.x;
    if (blockIdx.x < NB) {
        __shared__ float sh_v[SS];
        __shared__ float sh_part[8 * SS];
        __shared__ float sh_red[4];
        __shared__ __align__(16) float xbuf[2][XBF];
        const int n = blockIdx.x, nf = sup[n * 3 + 2];
        const int g = tid & 31, c = tid >> 5;
        float4 e[16];
        #pragma unroll
        for (int j = 0; j < 16; ++j) {
            const float4 t4 = *(const float4*)(trans + (size_t)(16 * c + j) * SS + 4 * g);
            e[j] = make_float4(__expf(t4.x), __expf(t4.y), __expf(t4.z), __expf(t4.w));
        }
        const int lab = (tid < SS) ? den_labels[tid & (SS - 1)] : 0;
        const float* xb = x + (size_t)n * TT * FF;
        {
            const float4* s0 = (const float4*)xb;
            float4 p0 = s0[tid]; float4 p1; if (tid < 104) p1 = s0[256 + tid];
            float4* d0 = (float4*)xbuf[0];
            d0[tid] = p0; if (tid < 104) d0[256 + tid] = p1;
        }
        if (tid < SS) sh_v[tid] = (tid == 0) ? 1.0f : 0.0f;
        float logM = 0.0f, v = 0.0f, pe = 0.0f;
        float4 pf0, pf1;
        __syncthreads();
        for (int t = 0; t < nf; ++t) {
            const int b = t >> 4;
            if (tid < SS) pe = __expf(xbuf[b & 1][(t & 15) * FF + lab]);
            float4 aa[4];
            { const float4* av = (const float4*)(sh_v + 16 * c);
              aa[0] = av[0]; aa[1] = av[1]; aa[2] = av[2]; aa[3] = av[3]; }
            const float* as = (const float*)aa;
            float4 acc = make_float4(0.f, 0.f, 0.f, 0.f);
            #pragma unroll
            for (int j = 0; j < 16; ++j) {
                acc.x = fmaf(as[j], e[j].x, acc.x); acc.y = fmaf(as[j], e[j].y, acc.y);
                acc.z = fmaf(as[j], e[j].z, acc.z); acc.w = fmaf(as[j], e[j].w, acc.w);
            }
            *(float4*)(sh_part + c * SS + 4 * g) = acc;
            if ((t & 15) == 8) {
                const int tn = (b + 1) * 16;
                if (tn < nf) {
                    const float4* s = (const float4*)(xb + (size_t)tn * FF);
                    pf0 = s[tid]; if (tid < 104) pf1 = s[256 + tid];
                }
            }
            __syncthreads();
            const bool rs = ((t & 15) == 15);
            if (tid < SS) {
                float y = 0.0f;
                #pragma unroll
                for (int cc = 0; cc < 8; ++cc) y += sh_part[cc * SS + tid];
                v = y * pe;
                if (rs) {
                    float m = v;
                    #pragma unroll
                    for (int off = 32; off >= 1; off >>= 1)
                        m = fmaxf(m, __shfl_xor(m, off, 64));
                    if ((tid & 63) == 0) sh_red[tid >> 6] = m;
                }
            }
            if (rs) {
                const int tn = (b + 1) * 16;
                if (tn < nf) {
                    float4* dst = (float4*)xbuf[(b + 1) & 1];
                    dst[tid] = pf0; if (tid < 104) dst[256 + tid] = pf1;
                }
                __syncthreads();
                if (tid < SS) {
                    float mm = fmaxf(fmaxf(sh_red[0], sh_red[1]), 1e-37f);
                    v *= (1.0f / mm); logM += __logf(mm);
                }
            }
            if (tid < SS) sh_v[tid] = v;
            __syncthreads();
        }
        if (tid < SS) {
            float ssum = v;
            #pragma unroll
            for (int off = 32; off >= 1; off >>= 1) ssum += __shfl_xor(ssum, off, 64);
            if ((tid & 63) == 0) sh_red[2 + (tid >> 6)] = ssum;
        }
        __syncthreads();
        if (tid == 0) ws[n] = logM + __logf(sh_red[2] + sh_red[3]);
    } else {
        const int w = tid >> 6, l = tid & 63;
        const int n = (blockIdx.x - NB) * 4 + w;
        const int nf = sup[n * 3 + 2];
        const float* xb = x + (size_t)n * TT * FF;
        const int* nl = num_labels + n * LL;
        int li[4];
        #pragma unroll
        for (int k = 0; k < 4; ++k) li[k] = nl[min(4 * l + k, LL - 1)];
        float a4[4] = {NEGV, NEGV, NEGV, NEGV};
        float ea[4], eb[4];
        #pragma unroll
        for (int k = 0; k < 4; ++k) ea[k] = xb[li[k]];
        { const float* xr = xb + (size_t)min(1, nf - 1) * FF;
          #pragma unroll
          for (int k = 0; k < 4; ++k) eb[k] = xr[li[k]]; }
        auto step = [&](float (&ee)[4], int t) {
            float left = __shfl_up(a4[3], 1, 64);
            if (l == 0) left = (t == 0) ? 0.0f : NEGV;
            float prev = left;
            #pragma unroll
            for (int k = 0; k < 4; ++k) {
                const float a = a4[k], b = prev;
                const float mx = fmaxf(a, b), mn = fminf(a, b);
                const float nv = mx + __logf(1.0f + __expf(mn - mx)) + ee[k];
                prev = a4[k]; a4[k] = nv;
            }
            const int t2 = min(t + 2, nf - 1);
            const float* xr = xb + (size_t)t2 * FF;
            #pragma unroll
            for (int k = 0; k < 4; ++k) ee[k] = xr[li[k]];
        };
        int t = 0;
        while (t < nf) { step(ea, t); ++t; if (t >= nf) break; step(eb, t); ++t; }
        const int idx = num_lens[n] - 1;
        if ((idx >> 2) == l) {
            const int kk = idx & 3;
            float vv = (kk == 0) ? a4[0] : (kk == 1) ? a4[1] : (kk == 2) ? a4[2] : a4[3];
            ws[NB + n] = vv;
        }
    }
}

extern "C" void kernel_launch(void* const* d_in, const int* in_sizes, int n_in,
                              void* d_out, int out_size, void* d_ws, size_t ws_size,
                              hipStream_t stream) {
    const float* x          = (const float*)d_in[0];
    const int*   sup        = (const int*)d_in[1];
    const float* trans      = (const float*)d_in[2];
    const int*   den_labels = (const int*)d_in[3];
    const int*   num_labels = (const int*)d_in[4];
    const int*   num_lens   = (const int*)d_in[5];
    float* out = (float*)d_out;

    const size_t PBYTES = (size_t)NB * DNODES * 32768;              // 8,388,608
    const size_t BBYTES = (size_t)NB * QNODES * 201 * BROW * 2;     // 5,351,424
    const size_t SCB    = (size_t)NB * DNODES * 8 * sizeof(float);  // 32,768
    const size_t SOFF   = PBYTES + BBYTES;
    const size_t AOFF   = SOFF + SCB + 64 * sizeof(float);
    const size_t NEEDED = AOFF + 2048 * 16;

    if (ws_size >= NEEDED) {
        unsigned*  Pout    = (unsigned*)d_ws;
        _Float16*  Bd      = (_Float16*)((char*)d_ws + PBYTES);
        float*     scales8 = (float*)((char*)d_ws + SOFF);
        float*     scores  = scales8 + NB * DNODES * 8;  // [0..15] den, [16..31] num
        unsigned*  AF      = (unsigned*)((char*)d_ws + AOFF);
        mmi_prep<<<dim3(8), dim3(256), 0, stream>>>(trans, AF);
        mmi_nodes<<<dim3(512), dim3(512), 0, stream>>>(
            x, sup, trans, den_labels, num_labels, AF, Pout, scales8, Bd);
        mmi_chain<<<dim3(2 * NB), dim3(256), 0, stream>>>(
            (const unsigned short*)d_ws, Bd, scales8, num_lens, scores);
        mmi_finalize<<<dim3(1), dim3(64), 0, stream>>>(scores, sup, out);
    } else {
        float* ws = (float*)d_ws;
        mmi_forward_fb<<<dim3(20), dim3(256), 0, stream>>>(
            x, sup, trans, den_labels, num_labels, num_lens, ws);
        mmi_finalize<<<dim3(1), dim3(64), 0, stream>>>(ws, sup, out);
    }
}